// Round 10
// baseline (563.834 us; speedup 1.0000x reference)
//
#include <hip/hip_runtime.h>
#include <cstdint>

#define B_   512
#define I_   2560
#define H_   512
#define E_   300
#define EW   320     // padded emb width
#define V_   8000
#define VPAD 8064    // 63 * 128
#define T_   16
#define G4H  2048
#define SOS_ 2

typedef _Float16 f16;
typedef _Float16 f16x8 __attribute__((ext_vector_type(8)));
typedef _Float16 f16x4 __attribute__((ext_vector_type(4)));
typedef float    f32x4 __attribute__((ext_vector_type(4)));

__device__ __forceinline__ float sigmoidf_(float x) {
    return 1.0f / (1.0f + __expf(-x));
}

__device__ __forceinline__ void gload16(const void* g, void* l) {
    __builtin_amdgcn_global_load_lds(
        (const __attribute__((address_space(1))) void*)g,
        (__attribute__((address_space(3))) void*)l,
        16, 0, 0);
}

// ---------------------------------------------------------------------------
// Generic MFMA f16 GEMM (m97 structure, verified rounds 2-9) — setup GEMMs.
// ---------------------------------------------------------------------------
__global__ __launch_bounds__(256)
void gemm_mfma(const f16* __restrict__ A, int lda,
               const f16* __restrict__ Bw, int ldb,
               float* __restrict__ C, int ldc,
               int K, int Nvalid,
               const float* __restrict__ bias1)
{
    __shared__ f16 As[128][32];
    __shared__ f16 Bs[128][32];

    const int tid  = threadIdx.x;
    const int w    = tid >> 6;
    const int lane = tid & 63;
    const int bm   = blockIdx.x * 128;
    const int bn   = blockIdx.y * 128;
    const int wr   = w >> 1;
    const int wc   = w & 1;

    const int srow = lane >> 2;
    const int skel = (lane & 3) * 8;

    const f16* Ag0 = A  + (size_t)(bm + w*32 +      srow) * lda + skel;
    const f16* Ag1 = A  + (size_t)(bm + w*32 + 16 + srow) * lda + skel;
    const f16* Bg0 = Bw + (size_t)(bn + w*32 +      srow) * ldb + skel;
    const f16* Bg1 = Bw + (size_t)(bn + w*32 + 16 + srow) * ldb + skel;
    f16* Al0 = &As[w*32     ][0];
    f16* Al1 = &As[w*32 + 16][0];
    f16* Bl0 = &Bs[w*32     ][0];
    f16* Bl1 = &Bs[w*32 + 16][0];

    const int frow = lane & 15;
    const int fk   = (lane >> 4) * 8;

    f32x4 acc[4][4] = {};

    for (int k0 = 0; k0 < K; k0 += 32) {
        gload16(Ag0 + k0, Al0);
        gload16(Ag1 + k0, Al1);
        gload16(Bg0 + k0, Bl0);
        gload16(Bg1 + k0, Bl1);
        __syncthreads();

        f16x8 af[4], bf[4];
        #pragma unroll
        for (int m = 0; m < 4; ++m)
            af[m] = *reinterpret_cast<const f16x8*>(&As[wr*64 + m*16 + frow][fk]);
        #pragma unroll
        for (int n = 0; n < 4; ++n)
            bf[n] = *reinterpret_cast<const f16x8*>(&Bs[wc*64 + n*16 + frow][fk]);

        #pragma unroll
        for (int m = 0; m < 4; ++m)
            #pragma unroll
            for (int n = 0; n < 4; ++n)
                acc[m][n] = __builtin_amdgcn_mfma_f32_16x16x32_f16(
                    af[m], bf[n], acc[m][n], 0, 0, 0);

        __syncthreads();
    }

    const int rowb = bm + wr*64 + (lane >> 4) * 4;
    #pragma unroll
    for (int n = 0; n < 4; ++n) {
        const int col = bn + wc*64 + n*16 + frow;
        if (col >= Nvalid) continue;
        const float badd = bias1 ? bias1[col] : 0.0f;
        #pragma unroll
        for (int m = 0; m < 4; ++m) {
            const int r0 = rowb + m*16;
            #pragma unroll
            for (int r = 0; r < 4; ++r)
                C[(size_t)(r0 + r) * ldc + col] = acc[m][n][r] + badd;
        }
    }
}

// ---------------------------------------------------------------------------
// ctx/cell-init GEMM (verified round 9): [512,1024] = fused16 @ [Win|Wcell]^T,
// fused epilogue writes ctx16 / h0(-1) / h1(-1) (+b_in) and c0/c1 (+b_cell).
// ---------------------------------------------------------------------------
__global__ __launch_bounds__(256)
void gemm_ctx_init(const f16* __restrict__ A,
                   const f16* __restrict__ Bw,
                   const float* __restrict__ b_in,
                   const float* __restrict__ b_cell,
                   f16* __restrict__ ctx16,
                   f16* __restrict__ h0, f16* __restrict__ h1,
                   float* __restrict__ c0, float* __restrict__ c1)
{
    __shared__ f16 As[128][32];
    __shared__ f16 Bs[128][32];

    const int tid  = threadIdx.x;
    const int w    = tid >> 6;
    const int lane = tid & 63;
    const int bm   = blockIdx.x * 128;
    const int bn   = blockIdx.y * 128;
    const int wr   = w >> 1;
    const int wc   = w & 1;

    const int srow = lane >> 2;
    const int skel = (lane & 3) * 8;

    const f16* Ag0 = A  + (size_t)(bm + w*32 +      srow) * I_ + skel;
    const f16* Ag1 = A  + (size_t)(bm + w*32 + 16 + srow) * I_ + skel;
    const f16* Bg0 = Bw + (size_t)(bn + w*32 +      srow) * I_ + skel;
    const f16* Bg1 = Bw + (size_t)(bn + w*32 + 16 + srow) * I_ + skel;
    f16* Al0 = &As[w*32     ][0];
    f16* Al1 = &As[w*32 + 16][0];
    f16* Bl0 = &Bs[w*32     ][0];
    f16* Bl1 = &Bs[w*32 + 16][0];

    const int frow = lane & 15;
    const int fk   = (lane >> 4) * 8;

    f32x4 acc[4][4] = {};

    for (int k0 = 0; k0 < I_; k0 += 32) {
        gload16(Ag0 + k0, Al0);
        gload16(Ag1 + k0, Al1);
        gload16(Bg0 + k0, Bl0);
        gload16(Bg1 + k0, Bl1);
        __syncthreads();

        f16x8 af[4], bf[4];
        #pragma unroll
        for (int m = 0; m < 4; ++m)
            af[m] = *reinterpret_cast<const f16x8*>(&As[wr*64 + m*16 + frow][fk]);
        #pragma unroll
        for (int n = 0; n < 4; ++n)
            bf[n] = *reinterpret_cast<const f16x8*>(&Bs[wc*64 + n*16 + frow][fk]);

        #pragma unroll
        for (int m = 0; m < 4; ++m)
            #pragma unroll
            for (int n = 0; n < 4; ++n)
                acc[m][n] = __builtin_amdgcn_mfma_f32_16x16x32_f16(
                    af[m], bf[n], acc[m][n], 0, 0, 0);

        __syncthreads();
    }

    const int rowb = bm + wr*64 + (lane >> 4) * 4;
    #pragma unroll
    for (int n = 0; n < 4; ++n) {
        const int col = bn + wc*64 + n*16 + frow;
        #pragma unroll
        for (int m = 0; m < 4; ++m) {
            const int r0 = rowb + m*16;
            #pragma unroll
            for (int r = 0; r < 4; ++r) {
                const int row = r0 + r;
                if (col < 512) {
                    const f16 ch = (f16)(acc[m][n][r] + b_in[col]);
                    ctx16[(size_t)row * 512 + col] = ch;
                    h0[(size_t)row * 512 + col] = ch;
                    h1[(size_t)row * 512 + col] = ch;
                } else {
                    const float cc = acc[m][n][r] + b_cell[col - 512];
                    c0[(size_t)row * 512 + col - 512] = cc;
                    c1[(size_t)row * 512 + col - 512] = cc;
                }
            }
        }
    }
}

// ---------------------------------------------------------------------------
// Recurrent GEMM + fused LSTM cell body, BK=32 / 24 KB LDS variant.
// LDS: Abuf 2x4K @0, Wbuf 2x8K @8K. Counted vmcnt depth-2 (steady vmcnt(3)).
// Epilogue: two-round half-exchange of f32 gates through [64][68] LDS.
// ---------------------------------------------------------------------------
__device__ __forceinline__ void gemm_cell_body(
    const f16* __restrict__ Ap1, const f16* __restrict__ Ap2, int lda2,
    const f16* __restrict__ Wp, int K,
    const float* __restrict__ Cadd,
    const float* __restrict__ bih, const float* __restrict__ bhh,
    float* __restrict__ cst,
    f16* __restrict__ hout1,
    char* smem, int bm, int bn)
{
    const int tid  = threadIdx.x;
    const int w    = tid >> 6;
    const int lane = tid & 63;
    const int wr   = w >> 1, wc = w & 1;
    const int frow = lane & 15, hi = lane >> 4;
    const int lrow = lane >> 2;                          // row within 16-row line
    const int ksb  = ((((lane & 3) * 16) ^ ((lrow & 3) << 4)) >> 1); // preswizzled k (f16)
    const int swr  = (frow & 3) << 4;                    // read-side swizzle (bytes)

    char* Abuf = smem;            // 2 x 4096
    char* Wbuf = smem + 8192;     // 2 x 8192

    const int NT = K >> 5;
    f32x4 acc[2][4] = {};

    auto stage = [&](int bsel, int kt) {
        const int k0 = kt << 5;
        {
            const int row = w*16 + lrow;
            const f16* src = (k0 < 512)
                ? Ap1 + (size_t)(bm + row) * 512 + k0 + ksb
                : Ap2 + (size_t)(bm + row) * lda2 + (k0 - 512) + ksb;
            gload16(src, Abuf + bsel*4096 + w*1024 + lane*16);
        }
        #pragma unroll
        for (int j = 0; j < 2; ++j) {
            const int row = w*32 + j*16 + lrow;
            gload16(Wp + (size_t)(bn + row) * K + k0 + ksb,
                    Wbuf + bsel*8192 + (w*2 + j)*1024 + lane*16);
        }
    };

    stage(0, 0);
    stage(1, 1);

    int buf = 0;
    for (int kt = 0; kt < NT; ++kt) {
        if (kt < NT - 1) asm volatile("s_waitcnt vmcnt(3)" ::: "memory");
        else             asm volatile("s_waitcnt vmcnt(0)" ::: "memory");
        __builtin_amdgcn_sched_barrier(0);
        __builtin_amdgcn_s_barrier();
        __builtin_amdgcn_sched_barrier(0);

        const char* A_ = Abuf + buf*4096;
        const char* W_ = Wbuf + buf*8192;
        f16x8 af[2], bf[4];
        #pragma unroll
        for (int m = 0; m < 2; ++m)
            af[m] = *reinterpret_cast<const f16x8*>(A_ + (wr*32 + m*16 + frow)*64 + ((hi*16) ^ swr));
        #pragma unroll
        for (int n = 0; n < 4; ++n)
            bf[n] = *reinterpret_cast<const f16x8*>(W_ + (wc*64 + n*16 + frow)*64 + ((hi*16) ^ swr));
        __builtin_amdgcn_sched_barrier(0);
        asm volatile("s_waitcnt lgkmcnt(0)" ::: "memory");
        __builtin_amdgcn_sched_barrier(0);
        __builtin_amdgcn_s_barrier();
        __builtin_amdgcn_sched_barrier(0);

        if (kt + 2 < NT) stage(buf, kt + 2);

        #pragma unroll
        for (int m = 0; m < 2; ++m)
            #pragma unroll
            for (int n = 0; n < 4; ++n)
                acc[m][n] = __builtin_amdgcn_mfma_f32_16x16x32_f16(
                    af[m], bf[n], acc[m][n], 0, 0, 0);
        buf ^= 1;
    }

    // ---- two-round half-exchange of gates (f32, [64][68] = 17.4 KB) ----
    float* gs = (float*)smem;
    if (wc == 0) {                              // gates i (cols 0..31), f (32..63)
        #pragma unroll
        for (int m = 0; m < 2; ++m) {
            const int row = wr*32 + m*16 + hi*4;
            #pragma unroll
            for (int n = 0; n < 4; ++n) {
                const int c = n*16 + frow;
                #pragma unroll
                for (int r = 0; r < 4; ++r) {
                    float v = acc[m][n][r];
                    if (Cadd) v += Cadd[(size_t)(bm + row + r) * G4H + bn + c];
                    gs[(row + r)*68 + c] = v;
                }
            }
        }
    }
    __syncthreads();
    const int hp = tid & 31;
    const int rb = (tid >> 5) * 8;
    const int hg = (bn >> 2) + hp;
    float g0v[8], g1v[8];
    #pragma unroll
    for (int i = 0; i < 8; ++i) {
        g0v[i] = gs[(rb + i)*68 + hp];
        g1v[i] = gs[(rb + i)*68 + 32 + hp];
    }
    __syncthreads();
    if (wc == 1) {                              // gates g (cols 64..95), o (96..127)
        #pragma unroll
        for (int m = 0; m < 2; ++m) {
            const int row = wr*32 + m*16 + hi*4;
            #pragma unroll
            for (int n = 0; n < 4; ++n) {
                const int c = n*16 + frow;
                #pragma unroll
                for (int r = 0; r < 4; ++r) {
                    float v = acc[m][n][r];
                    if (Cadd) v += Cadd[(size_t)(bm + row + r) * G4H + bn + 64 + c];
                    gs[(row + r)*68 + c] = v;
                }
            }
        }
    }
    __syncthreads();

    float bi0 = 0.f, bi1 = 0.f, bi2 = 0.f, bi3 = 0.f;
    if (bih) {
        bi0 = bih[hg]        + bhh[hg];
        bi1 = bih[512 + hg]  + bhh[512 + hg];
        bi2 = bih[1024 + hg] + bhh[1024 + hg];
        bi3 = bih[1536 + hg] + bhh[1536 + hg];
    }
    #pragma unroll
    for (int i = 0; i < 8; ++i) {
        const int r = rb + i;
        const int b = bm + r;
        const float gi = g0v[i] + bi0;
        const float gf = g1v[i] + bi1;
        const float gc = gs[r*68 + hp] + bi2;
        const float go = gs[r*68 + 32 + hp] + bi3;
        const float c  = cst[(size_t)b * 512 + hg];
        const float cn = sigmoidf_(gf) * c + sigmoidf_(gi) * tanhf(gc);
        const float hn = sigmoidf_(go) * tanhf(cn);
        cst[(size_t)b * 512 + hg] = cn;
        hout1[(size_t)b * 512 + hg] = (f16)hn;
    }
}

// ---------------------------------------------------------------------------
// Output-projection tile body, BK=32 / 32 KB LDS: A 2x8K @0, W 2x8K @16K.
// Counted vmcnt depth-2 (steady vmcnt(4)), nontemporal C stores.
// ---------------------------------------------------------------------------
__device__ __forceinline__ void gemm_out_body(
    const f16* __restrict__ A, const f16* __restrict__ Bw,
    float* __restrict__ C,     // = out + t*V_
    const float* __restrict__ bias,
    int bm, int bn, char* smem, int tid)
{
    const int w    = tid >> 6;
    const int lane = tid & 63;
    const int wr   = w >> 1, wc = w & 1;
    const int frow = lane & 15, hi = lane >> 4;
    const int lrow = lane >> 2;
    const int ksb  = ((((lane & 3) * 16) ^ ((lrow & 3) << 4)) >> 1);
    const int swr  = (frow & 3) << 4;

    char* Abuf = smem;            // 2 x 8192
    char* Wbuf = smem + 16384;    // 2 x 8192
    f32x4 acc[4][4] = {};

    auto stage = [&](int bsel, int kt) {
        const int k0 = kt << 5;
        #pragma unroll
        for (int j = 0; j < 2; ++j) {
            const int row = w*32 + j*16 + lrow;
            gload16(A  + (size_t)(bm + row) * 512 + k0 + ksb,
                    Abuf + bsel*8192 + (w*2 + j)*1024 + lane*16);
            gload16(Bw + (size_t)(bn + row) * 512 + k0 + ksb,
                    Wbuf + bsel*8192 + (w*2 + j)*1024 + lane*16);
        }
    };

    stage(0, 0);
    stage(1, 1);

    int buf = 0;
    for (int kt = 0; kt < 16; ++kt) {
        if (kt < 15) asm volatile("s_waitcnt vmcnt(4)" ::: "memory");
        else         asm volatile("s_waitcnt vmcnt(0)" ::: "memory");
        __builtin_amdgcn_sched_barrier(0);
        __builtin_amdgcn_s_barrier();
        __builtin_amdgcn_sched_barrier(0);

        const char* A_ = Abuf + buf*8192;
        const char* W_ = Wbuf + buf*8192;
        f16x8 af[4], bf[4];
        #pragma unroll
        for (int m = 0; m < 4; ++m)
            af[m] = *reinterpret_cast<const f16x8*>(A_ + (wr*64 + m*16 + frow)*64 + ((hi*16) ^ swr));
        #pragma unroll
        for (int n = 0; n < 4; ++n)
            bf[n] = *reinterpret_cast<const f16x8*>(W_ + (wc*64 + n*16 + frow)*64 + ((hi*16) ^ swr));
        __builtin_amdgcn_sched_barrier(0);
        asm volatile("s_waitcnt lgkmcnt(0)" ::: "memory");
        __builtin_amdgcn_sched_barrier(0);
        __builtin_amdgcn_s_barrier();
        __builtin_amdgcn_sched_barrier(0);

        if (kt + 2 < 16) stage(buf, kt + 2);

        #pragma unroll
        for (int m = 0; m < 4; ++m)
            #pragma unroll
            for (int n = 0; n < 4; ++n)
                acc[m][n] = __builtin_amdgcn_mfma_f32_16x16x32_f16(
                    af[m], bf[n], acc[m][n], 0, 0, 0);
        buf ^= 1;
    }

    const int rowb = bm + wr*64 + hi*4;
    #pragma unroll
    for (int n = 0; n < 4; ++n) {
        const int col = bn + wc*64 + n*16 + frow;
        if (col >= V_) continue;
        const float badd = bias[col];
        #pragma unroll
        for (int m = 0; m < 4; ++m) {
            const int r0 = rowb + m*16;
            #pragma unroll
            for (int r = 0; r < 4; ++r)
                __builtin_nontemporal_store(
                    acc[m][n][r] + badd,
                    &C[(size_t)(r0 + r) * (T_ * V_) + col]);
        }
    }
}

// ---------------------------------------------------------------------------
// Fused phase kernel: 512 blocks, 32 KB LDS -> 2+ blocks/CU co-resident.
// XCD-aware bn ownership as round 8/9.
// ---------------------------------------------------------------------------
__global__ __launch_bounds__(256)
void phase_kernel(const f16* __restrict__ h0in,
                  const f16* __restrict__ embt,
                  f16* __restrict__ h0out,
                  const f16* __restrict__ h1in,
                  f16* __restrict__ h1out,
                  const f16* __restrict__ W0p, const f16* __restrict__ W1p,
                  const f16* __restrict__ WoutP,
                  const float* __restrict__ ctxg,
                  const float* __restrict__ bih1, const float* __restrict__ bhh1,
                  const float* __restrict__ b_out,
                  float* __restrict__ c0, float* __restrict__ c1,
                  float* __restrict__ out, int tout,
                  int active0, int active1, int activeO)
{
    __shared__ char smem[32768];
    const int bx = blockIdx.x;

    if (bx < 128) {
        if (!active0) return;
        const int xcd = bx & 7, idx = bx >> 3;
        const int bn = (xcd*2 + (idx & 1)) * 128;
        const int bm = (idx >> 1) * 64;
        gemm_cell_body(h0in, embt, EW, W0p, 832,
                       ctxg, nullptr, nullptr, c0, h0out, smem, bm, bn);
    } else if (bx < 256) {
        if (!active1) return;
        const int lb = bx - 128;
        const int xcd = lb & 7, idx = lb >> 3;
        const int bn = (xcd*2 + (idx & 1)) * 128;
        const int bm = (idx >> 1) * 64;
        gemm_cell_body(h0in, h1in, 512, W1p, 1024,
                       nullptr, bih1, bhh1, c1, h1out, smem, bm, bn);
    } else {
        if (!activeO) return;
        const int o = bx - 256;                  // 0..255
        const int xcd = o & 7, j = o >> 3;       // j 0..31
        const int bnt = xcd*8 + (j >> 2);        // 0..63
        if (bnt >= 63) return;                   // 4 idle blocks
        const int bm = (j & 3) * 128;
        gemm_out_body(h1in, WoutP, out + (size_t)tout * V_, b_out,
                      bm, bnt * 128, smem, threadIdx.x);
    }
}

// ---------------------------------------------------------------------------
// ONE merged setup kernel (verified round 9).
// ---------------------------------------------------------------------------
#define NB_F16   1280
#define NB_WIC   2560
#define NB_W0    6656
#define NB_W1    8192
#define NB_WCTX  4096
#define NB_B0    8
#define NB_WOUT  4032
#define NB_EMB   10240
#define NB_TOTAL (NB_F16+NB_WIC+NB_W0+NB_W1+NB_WCTX+NB_B0+NB_WOUT+NB_EMB)

__global__ __launch_bounds__(256)
void pack_all(const float* __restrict__ fused,
              const float* __restrict__ Win, const float* __restrict__ Wcell,
              const float* __restrict__ Whh0, const float* __restrict__ Wih0,
              const float* __restrict__ Wih1, const float* __restrict__ Whh1,
              const float* __restrict__ bih0, const float* __restrict__ bhh0,
              const float* __restrict__ Wout,
              const float* __restrict__ emb, const int* __restrict__ target,
              f16* __restrict__ fused16, f16* __restrict__ WinCell,
              f16* __restrict__ W0, f16* __restrict__ W1,
              f16* __restrict__ Wc, float* __restrict__ b01p,
              f16* __restrict__ Wo, f16* __restrict__ embAll)
{
    int bx = blockIdx.x;
    const int tid = threadIdx.x;

    if (bx < NB_F16) {
        const int i = bx * 256 + tid;
        const float4 v = reinterpret_cast<const float4*>(fused)[i];
        f16x4 h = { (f16)v.x, (f16)v.y, (f16)v.z, (f16)v.w };
        *reinterpret_cast<f16x4*>(fused16 + (size_t)i * 4) = h;
        return;
    }
    bx -= NB_F16;
    if (bx < NB_WIC) {
        const int i = bx * 256 + tid;
        const int r = i / 640, c4 = (i % 640) * 4;
        const float* src = (r < 512) ? Win + (size_t)r * I_ + c4
                                     : Wcell + (size_t)(r - 512) * I_ + c4;
        const float4 v = *reinterpret_cast<const float4*>(src);
        f16x4 h = { (f16)v.x, (f16)v.y, (f16)v.z, (f16)v.w };
        *reinterpret_cast<f16x4*>(WinCell + (size_t)i * 4) = h;
        return;
    }
    bx -= NB_WIC;
    if (bx < NB_W0) {
        const int idx = bx * 256 + tid;
        const int rp = idx / 832, k = idx % 832;
        const int g = (rp >> 5) & 3, h = (rp >> 7) * 32 + (rp & 31);
        const int srow = g * 512 + h;
        float v;
        if (k < 512)      v = Whh0[(size_t)srow * 512 + k];
        else if (k < 812) v = Wih0[(size_t)srow * 812 + (k - 512)];
        else              v = 0.0f;
        W0[idx] = (f16)v;
        return;
    }
    bx -= NB_W0;
    if (bx < NB_W1) {
        const int idx = bx * 256 + tid;
        const int rp = idx >> 10, k = idx & 1023;
        const int g = (rp >> 5) & 3, h = (rp >> 7) * 32 + (rp & 31);
        const int srow = g * 512 + h;
        const float v = (k < 512) ? Wih1[(size_t)srow * 512 + k]
                                  : Whh1[(size_t)srow * 512 + (k - 512)];
        W1[idx] = (f16)v;
        return;
    }
    bx -= NB_W1;
    if (bx < NB_WCTX) {
        const int idx = bx * 256 + tid;
        const int rp = idx >> 9, k = idx & 511;
        const int g = (rp >> 5) & 3, h = (rp >> 7) * 32 + (rp & 31);
        Wc[idx] = (f16)Wih0[(size_t)(g * 512 + h) * 812 + 300 + k];
        return;
    }
    bx -= NB_WCTX;
    if (bx < NB_B0) {
        const int idx = bx * 256 + tid;
        const int g = (idx >> 5) & 3, h = (idx >> 7) * 32 + (idx & 31);
        b01p[idx] = bih0[g * 512 + h] + bhh0[g * 512 + h];
        return;
    }
    bx -= NB_B0;
    if (bx < NB_WOUT) {
        const int i = bx * 256 + tid;
        const int r = i >> 7, c4 = (i & 127) * 4;
        f16x4 h = { (f16)0.f, (f16)0.f, (f16)0.f, (f16)0.f };
        if (r < V_) {
            const float4 v = *reinterpret_cast<const float4*>(Wout + (size_t)r * H_ + c4);
            h = f16x4{ (f16)v.x, (f16)v.y, (f16)v.z, (f16)v.w };
        }
        *reinterpret_cast<f16x4*>(Wo + (size_t)i * 4) = h;
        return;
    }
    bx -= NB_WOUT;
    {
        const int idx = bx * 256 + tid;
        const int t = idx / (B_ * EW);
        const int rem = idx % (B_ * EW);
        const int b = rem / EW, e = rem % EW;
        const int wd = (t == 0) ? SOS_ : target[b * T_ + (t - 1)];
        const float v = (e < E_) ? emb[(size_t)wd * E_ + e] : 0.0f;
        embAll[idx] = (f16)v;
    }
}

// ---------------------------------------------------------------------------
extern "C" void kernel_launch(void* const* d_in, const int* in_sizes, int n_in,
                              void* d_out, int out_size, void* d_ws, size_t ws_size,
                              hipStream_t stream)
{
    const float* fused  = (const float*)d_in[0];
    const int*   target = (const int*)d_in[1];
    const float* emb    = (const float*)d_in[3];
    const float* W_in   = (const float*)d_in[4];
    const float* b_in   = (const float*)d_in[5];
    const float* W_cell = (const float*)d_in[6];
    const float* b_cell = (const float*)d_in[7];
    const float* W_ih0  = (const float*)d_in[8];
    const float* W_hh0  = (const float*)d_in[9];
    const float* b_ih0  = (const float*)d_in[10];
    const float* b_hh0  = (const float*)d_in[11];
    const float* W_ih1  = (const float*)d_in[12];
    const float* W_hh1  = (const float*)d_in[13];
    const float* b_ih1  = (const float*)d_in[14];
    const float* b_hh1  = (const float*)d_in[15];
    const float* W_out  = (const float*)d_in[16];
    const float* b_out  = (const float*)d_in[17];
    float* out = (float*)d_out;

    char* p = (char*)d_ws;
    auto carve = [&](size_t bytes) {
        char* r = p;
        p += (bytes + 255) & ~(size_t)255;
        return r;
    };
    float* ctxg   = (float*)carve((size_t)B_ * G4H * 4);
    float* b01p   = (float*)carve((size_t)G4H * 4);
    float* c0     = (float*)carve((size_t)B_ * H_ * 4);
    float* c1     = (float*)carve((size_t)B_ * H_ * 4);
    f16* fused16  = (f16*)carve((size_t)B_ * I_ * 2);
    f16* WinCell  = (f16*)carve((size_t)1024 * I_ * 2);
    f16* W0p      = (f16*)carve((size_t)G4H * 832 * 2);
    f16* W1p      = (f16*)carve((size_t)G4H * 1024 * 2);
    f16* Wctxp    = (f16*)carve((size_t)G4H * H_ * 2);
    f16* Wout16   = (f16*)carve((size_t)VPAD * H_ * 2);
    f16* ctx16    = (f16*)carve((size_t)B_ * H_ * 2);
    f16* h0a      = (f16*)carve((size_t)B_ * H_ * 2);
    f16* h0b      = (f16*)carve((size_t)B_ * H_ * 2);
    f16* h1a      = (f16*)carve((size_t)B_ * H_ * 2);
    f16* h1b      = (f16*)carve((size_t)B_ * H_ * 2);
    f16* embAll   = (f16*)carve((size_t)T_ * B_ * EW * 2);

    // ---- 1 merged pack launch ----
    pack_all<<<dim3(NB_TOTAL), 256, 0, stream>>>(
        fused, W_in, W_cell, W_hh0, W_ih0, W_ih1, W_hh1,
        b_ih0, b_hh0, W_out, emb, target,
        fused16, WinCell, W0p, W1p, Wctxp, b01p, Wout16, embAll);

    // ---- ctx/cell-init GEMM with fused init epilogue ----
    gemm_ctx_init<<<dim3(B_/128, 1024/128), 256, 0, stream>>>(
        fused16, WinCell, b_in, b_cell, ctx16, h0b, h1b, c0, c1);

    // ---- time-invariant ctx gate contribution (+ b0 biases) ----
    gemm_mfma<<<dim3(B_/128, G4H/128), 256, 0, stream>>>(
        ctx16, H_, Wctxp, H_, ctxg, G4H, H_, G4H, b01p);

    // ---- skewed recurrent + fused out-projection: phases 0..17 ----
    f16* h0buf[2] = { h0a, h0b };
    f16* h1buf[2] = { h1a, h1b };
    for (int phase = 0; phase <= T_ + 1; ++phase) {
        const int a0 = (phase < T_) ? 1 : 0;
        const int a1 = (phase >= 1 && phase <= T_) ? 1 : 0;
        const int aO = (phase >= 2) ? 1 : 0;
        const int te = (phase < T_) ? phase : (T_ - 1);
        const int tO = aO ? (phase - 2) : 0;
        phase_kernel<<<dim3(512), 256, 0, stream>>>(
            h0buf[(phase + 1) & 1],
            embAll + (size_t)te * B_ * EW,
            h0buf[phase & 1],
            h1buf[phase & 1],
            h1buf[(phase + 1) & 1],
            W0p, W1p, Wout16, ctxg, b_ih1, b_hh1, b_out,
            c0, c1, out, tO, a0, a1, aO);
    }
}

// Round 11
// 417.596 us; speedup vs baseline: 1.3502x; 1.3502x over previous
//
#include <hip/hip_runtime.h>
#include <cstdint>

#define B_   512
#define I_   2560
#define H_   512
#define E_   300
#define EW   320     // padded emb width
#define V_   8000
#define VPAD 8064    // 63 * 128
#define T_   16
#define G4H  2048
#define SOS_ 2

typedef _Float16 f16;
typedef _Float16 f16x8 __attribute__((ext_vector_type(8)));
typedef _Float16 f16x4 __attribute__((ext_vector_type(4)));
typedef float    f32x4 __attribute__((ext_vector_type(4)));

__device__ __forceinline__ float sigmoidf_(float x) {
    return 1.0f / (1.0f + __expf(-x));
}

__device__ __forceinline__ void gload16(const void* g, void* l) {
    __builtin_amdgcn_global_load_lds(
        (const __attribute__((address_space(1))) void*)g,
        (__attribute__((address_space(3))) void*)l,
        16, 0, 0);
}

// ---------------------------------------------------------------------------
// MFMA f16 GEMM (m97 structure) writing f16 C (+f32 bias) — ctxg producer.
// ---------------------------------------------------------------------------
__global__ __launch_bounds__(256)
void gemm_mfma_f16o(const f16* __restrict__ A, int lda,
                    const f16* __restrict__ Bw, int ldb,
                    f16* __restrict__ C, int ldc,
                    int K,
                    const float* __restrict__ bias1)
{
    __shared__ f16 As[128][32];
    __shared__ f16 Bs[128][32];

    const int tid  = threadIdx.x;
    const int w    = tid >> 6;
    const int lane = tid & 63;
    const int bm   = blockIdx.x * 128;
    const int bn   = blockIdx.y * 128;
    const int wr   = w >> 1;
    const int wc   = w & 1;

    const int srow = lane >> 2;
    const int skel = (lane & 3) * 8;

    const f16* Ag0 = A  + (size_t)(bm + w*32 +      srow) * lda + skel;
    const f16* Ag1 = A  + (size_t)(bm + w*32 + 16 + srow) * lda + skel;
    const f16* Bg0 = Bw + (size_t)(bn + w*32 +      srow) * ldb + skel;
    const f16* Bg1 = Bw + (size_t)(bn + w*32 + 16 + srow) * ldb + skel;
    f16* Al0 = &As[w*32     ][0];
    f16* Al1 = &As[w*32 + 16][0];
    f16* Bl0 = &Bs[w*32     ][0];
    f16* Bl1 = &Bs[w*32 + 16][0];

    const int frow = lane & 15;
    const int fk   = (lane >> 4) * 8;

    f32x4 acc[4][4] = {};

    for (int k0 = 0; k0 < K; k0 += 32) {
        gload16(Ag0 + k0, Al0);
        gload16(Ag1 + k0, Al1);
        gload16(Bg0 + k0, Bl0);
        gload16(Bg1 + k0, Bl1);
        __syncthreads();

        f16x8 af[4], bf[4];
        #pragma unroll
        for (int m = 0; m < 4; ++m)
            af[m] = *reinterpret_cast<const f16x8*>(&As[wr*64 + m*16 + frow][fk]);
        #pragma unroll
        for (int n = 0; n < 4; ++n)
            bf[n] = *reinterpret_cast<const f16x8*>(&Bs[wc*64 + n*16 + frow][fk]);

        #pragma unroll
        for (int m = 0; m < 4; ++m)
            #pragma unroll
            for (int n = 0; n < 4; ++n)
                acc[m][n] = __builtin_amdgcn_mfma_f32_16x16x32_f16(
                    af[m], bf[n], acc[m][n], 0, 0, 0);

        __syncthreads();
    }

    const int rowb = bm + wr*64 + (lane >> 4) * 4;
    #pragma unroll
    for (int n = 0; n < 4; ++n) {
        const int col = bn + wc*64 + n*16 + frow;
        const float badd = bias1 ? bias1[col] : 0.0f;
        #pragma unroll
        for (int m = 0; m < 4; ++m) {
            const int r0 = rowb + m*16;
            #pragma unroll
            for (int r = 0; r < 4; ++r)
                C[(size_t)(r0 + r) * ldc + col] = (f16)(acc[m][n][r] + badd);
        }
    }
}

// ---------------------------------------------------------------------------
// ctx/cell-init GEMM (verified rounds 9): [512,1024] = fused16 @ [Win|Wcell]^T,
// fused epilogue writes ctx16 / h0(-1) / h1(-1) (+b_in) and c0/c1 (+b_cell).
// ---------------------------------------------------------------------------
__global__ __launch_bounds__(256)
void gemm_ctx_init(const f16* __restrict__ A,
                   const f16* __restrict__ Bw,
                   const float* __restrict__ b_in,
                   const float* __restrict__ b_cell,
                   f16* __restrict__ ctx16,
                   f16* __restrict__ h0, f16* __restrict__ h1,
                   float* __restrict__ c0, float* __restrict__ c1)
{
    __shared__ f16 As[128][32];
    __shared__ f16 Bs[128][32];

    const int tid  = threadIdx.x;
    const int w    = tid >> 6;
    const int lane = tid & 63;
    const int bm   = blockIdx.x * 128;
    const int bn   = blockIdx.y * 128;
    const int wr   = w >> 1;
    const int wc   = w & 1;

    const int srow = lane >> 2;
    const int skel = (lane & 3) * 8;

    const f16* Ag0 = A  + (size_t)(bm + w*32 +      srow) * I_ + skel;
    const f16* Ag1 = A  + (size_t)(bm + w*32 + 16 + srow) * I_ + skel;
    const f16* Bg0 = Bw + (size_t)(bn + w*32 +      srow) * I_ + skel;
    const f16* Bg1 = Bw + (size_t)(bn + w*32 + 16 + srow) * I_ + skel;
    f16* Al0 = &As[w*32     ][0];
    f16* Al1 = &As[w*32 + 16][0];
    f16* Bl0 = &Bs[w*32     ][0];
    f16* Bl1 = &Bs[w*32 + 16][0];

    const int frow = lane & 15;
    const int fk   = (lane >> 4) * 8;

    f32x4 acc[4][4] = {};

    for (int k0 = 0; k0 < I_; k0 += 32) {
        gload16(Ag0 + k0, Al0);
        gload16(Ag1 + k0, Al1);
        gload16(Bg0 + k0, Bl0);
        gload16(Bg1 + k0, Bl1);
        __syncthreads();

        f16x8 af[4], bf[4];
        #pragma unroll
        for (int m = 0; m < 4; ++m)
            af[m] = *reinterpret_cast<const f16x8*>(&As[wr*64 + m*16 + frow][fk]);
        #pragma unroll
        for (int n = 0; n < 4; ++n)
            bf[n] = *reinterpret_cast<const f16x8*>(&Bs[wc*64 + n*16 + frow][fk]);

        #pragma unroll
        for (int m = 0; m < 4; ++m)
            #pragma unroll
            for (int n = 0; n < 4; ++n)
                acc[m][n] = __builtin_amdgcn_mfma_f32_16x16x32_f16(
                    af[m], bf[n], acc[m][n], 0, 0, 0);

        __syncthreads();
    }

    const int rowb = bm + wr*64 + (lane >> 4) * 4;
    #pragma unroll
    for (int n = 0; n < 4; ++n) {
        const int col = bn + wc*64 + n*16 + frow;
        #pragma unroll
        for (int m = 0; m < 4; ++m) {
            const int r0 = rowb + m*16;
            #pragma unroll
            for (int r = 0; r < 4; ++r) {
                const int row = r0 + r;
                if (col < 512) {
                    const f16 ch = (f16)(acc[m][n][r] + b_in[col]);
                    ctx16[(size_t)row * 512 + col] = ch;
                    h0[(size_t)row * 512 + col] = ch;
                    h1[(size_t)row * 512 + col] = ch;
                } else {
                    const float cc = acc[m][n][r] + b_cell[col - 512];
                    c0[(size_t)row * 512 + col - 512] = cc;
                    c1[(size_t)row * 512 + col - 512] = cc;
                }
            }
        }
    }
}

// ---------------------------------------------------------------------------
// Recurrent GEMM + fused LSTM cell body: round-9 structure (BK=64, XOR
// preswizzle, counted vmcnt) upgraded to DEPTH-3 prefetch.
// LDS: Abuf 3x8K @0, Wbuf 3x16K @24K (72 KB). vmcnt = 6*min(2, NT-1-kt).
// ---------------------------------------------------------------------------
__device__ __forceinline__ void gemm_cell_body(
    const f16* __restrict__ Ap1, const f16* __restrict__ Ap2, int lda2,
    const f16* __restrict__ Wp, int K,
    const f16* __restrict__ Cadd,
    const float* __restrict__ bih, const float* __restrict__ bhh,
    float* __restrict__ cst,
    f16* __restrict__ hout1,
    char* smem, int bm, int bn)
{
    const int tid  = threadIdx.x;
    const int w    = tid >> 6;
    const int lane = tid & 63;
    const int wr   = w >> 1, wc = w & 1;
    const int frow = lane & 15, hi = lane >> 4;
    const int sw   = (frow & 7) << 4;
    const int srow8 = lane >> 3;
    const int ksb  = ((((lane & 7) * 16) ^ (srow8 << 4)) >> 1);

    const int NT = K >> 6;
    f32x4 acc[2][4] = {};

    char* Abuf = smem;            // 3 x 8192
    char* Wbuf = smem + 24576;    // 3 x 16384

    auto stage = [&](int bsel, int kt) {
        const int k0 = kt << 6;
        #pragma unroll
        for (int j = 0; j < 2; ++j) {
            const int row = w*16 + j*8 + srow8;
            const f16* src;
            if (k0 < 512) src = Ap1 + (size_t)(bm + row) * 512  + k0 + ksb;
            else          src = Ap2 + (size_t)(bm + row) * lda2 + (k0 - 512) + ksb;
            gload16(src, Abuf + bsel*8192 + (w*2 + j)*1024 + lane*16);
        }
        #pragma unroll
        for (int j = 0; j < 4; ++j) {
            const int row = w*32 + j*8 + srow8;
            gload16(Wp + (size_t)(bn + row) * K + k0 + ksb,
                    Wbuf + bsel*16384 + (w*4 + j)*1024 + lane*16);
        }
    };

    stage(0, 0);
    stage(1, 1);
    stage(2, 2);

    int buf = 0;
    for (int kt = 0; kt < NT; ++kt) {
        const int rem = NT - 1 - kt;
        if (rem >= 2)      asm volatile("s_waitcnt vmcnt(12)" ::: "memory");
        else if (rem == 1) asm volatile("s_waitcnt vmcnt(6)" ::: "memory");
        else               asm volatile("s_waitcnt vmcnt(0)" ::: "memory");
        __builtin_amdgcn_sched_barrier(0);
        __builtin_amdgcn_s_barrier();
        __builtin_amdgcn_sched_barrier(0);

        const char* A_ = Abuf + buf*8192;
        const char* W_ = Wbuf + buf*16384;
        f16x8 af[2][2], bf[2][4];
        #pragma unroll
        for (int ks = 0; ks < 2; ++ks) {
            const int cb = (ks*64 + hi*16) ^ sw;
            #pragma unroll
            for (int m = 0; m < 2; ++m)
                af[ks][m] = *reinterpret_cast<const f16x8*>(A_ + (wr*32 + m*16 + frow)*128 + cb);
            #pragma unroll
            for (int n = 0; n < 4; ++n)
                bf[ks][n] = *reinterpret_cast<const f16x8*>(W_ + (wc*64 + n*16 + frow)*128 + cb);
        }
        __builtin_amdgcn_sched_barrier(0);
        asm volatile("s_waitcnt lgkmcnt(0)" ::: "memory");
        __builtin_amdgcn_sched_barrier(0);
        __builtin_amdgcn_s_barrier();
        __builtin_amdgcn_sched_barrier(0);

        if (kt + 3 < NT) stage(buf, kt + 3);

        #pragma unroll
        for (int ks = 0; ks < 2; ++ks)
            #pragma unroll
            for (int m = 0; m < 2; ++m)
                #pragma unroll
                for (int n = 0; n < 4; ++n)
                    acc[m][n] = __builtin_amdgcn_mfma_f32_16x16x32_f16(
                        af[ks][m], bf[ks][n], acc[m][n], 0, 0, 0);
        buf = (buf == 2) ? 0 : buf + 1;
    }

    // gates -> LDS (+ Cadd f16), f32 [64][132]
    float* gs = (float*)smem;
    #pragma unroll
    for (int m = 0; m < 2; ++m) {
        const int row = wr*32 + m*16 + hi*4;
        #pragma unroll
        for (int n = 0; n < 4; ++n) {
            const int col = wc*64 + n*16 + frow;
            #pragma unroll
            for (int r = 0; r < 4; ++r) {
                float v = acc[m][n][r];
                if (Cadd) v += (float)Cadd[(size_t)(bm + row + r) * G4H + bn + col];
                gs[(row + r)*132 + col] = v;
            }
        }
    }
    __syncthreads();

    const int hp = tid & 31;
    const int hg = (bn >> 2) + hp;
    float bi0 = 0.f, bi1 = 0.f, bi2 = 0.f, bi3 = 0.f;
    if (bih) {
        bi0 = bih[hg]        + bhh[hg];
        bi1 = bih[512 + hg]  + bhh[512 + hg];
        bi2 = bih[1024 + hg] + bhh[1024 + hg];
        bi3 = bih[1536 + hg] + bhh[1536 + hg];
    }
    #pragma unroll
    for (int i = 0; i < 8; ++i) {
        const int r = (tid >> 5) * 8 + i;
        const int b = bm + r;
        const float gi = gs[r*132 +      hp] + bi0;
        const float gf = gs[r*132 + 32 + hp] + bi1;
        const float gc = gs[r*132 + 64 + hp] + bi2;
        const float go = gs[r*132 + 96 + hp] + bi3;
        const float c  = cst[(size_t)b * 512 + hg];
        const float cn = sigmoidf_(gf) * c + sigmoidf_(gi) * tanhf(gc);
        const float hn = sigmoidf_(go) * tanhf(cn);
        cst[(size_t)b * 512 + hg] = cn;
        hout1[(size_t)b * 512 + hg] = (f16)hn;
    }
}

// ---------------------------------------------------------------------------
// Output-projection tile body (round-9 verified): BK=64, XOR-swizzled,
// depth-2 counted vmcnt, nontemporal C stores. LDS: A 2x16K @0, W 2x16K @32K.
// ---------------------------------------------------------------------------
__device__ __forceinline__ void gemm_out_body(
    const f16* __restrict__ A, const f16* __restrict__ Bw,
    float* __restrict__ C,     // = out + t*V_
    const float* __restrict__ bias,
    int bm, int bn, char* smem, int tid)
{
    const int w    = tid >> 6;
    const int lane = tid & 63;
    const int wr   = w >> 1, wc = w & 1;
    const int frow = lane & 15, hi = lane >> 4;
    const int sw   = (frow & 7) << 4;
    const int srow8 = lane >> 3;
    const int ksb  = ((((lane & 7) * 16) ^ (srow8 << 4)) >> 1);

    char* Abuf = smem;            // 2 x 16384
    char* Wbuf = smem + 32768;    // 2 x 16384
    f32x4 acc[4][4] = {};

    auto stage = [&](int bsel, int kt) {
        const int k0 = kt << 6;
        #pragma unroll
        for (int j = 0; j < 4; ++j) {
            const int row = w*32 + j*8 + srow8;
            gload16(A  + (size_t)(bm + row) * 512 + k0 + ksb,
                    Abuf + bsel*16384 + (w*4 + j)*1024 + lane*16);
            gload16(Bw + (size_t)(bn + row) * 512 + k0 + ksb,
                    Wbuf + bsel*16384 + (w*4 + j)*1024 + lane*16);
        }
    };

    stage(0, 0);
    stage(1, 1);

    int buf = 0;
    for (int kt = 0; kt < 8; ++kt) {
        if (kt < 7) asm volatile("s_waitcnt vmcnt(8)" ::: "memory");
        else        asm volatile("s_waitcnt vmcnt(0)" ::: "memory");
        __builtin_amdgcn_sched_barrier(0);
        __builtin_amdgcn_s_barrier();
        __builtin_amdgcn_sched_barrier(0);

        const char* A_ = Abuf + buf*16384;
        const char* W_ = Wbuf + buf*16384;
        f16x8 af[2][4], bf[2][4];
        #pragma unroll
        for (int ks = 0; ks < 2; ++ks) {
            const int cb = (ks*64 + hi*16) ^ sw;
            #pragma unroll
            for (int m = 0; m < 4; ++m)
                af[ks][m] = *reinterpret_cast<const f16x8*>(A_ + (wr*64 + m*16 + frow)*128 + cb);
            #pragma unroll
            for (int n = 0; n < 4; ++n)
                bf[ks][n] = *reinterpret_cast<const f16x8*>(W_ + (wc*64 + n*16 + frow)*128 + cb);
        }
        __builtin_amdgcn_sched_barrier(0);
        asm volatile("s_waitcnt lgkmcnt(0)" ::: "memory");
        __builtin_amdgcn_sched_barrier(0);
        __builtin_amdgcn_s_barrier();
        __builtin_amdgcn_sched_barrier(0);

        if (kt + 2 < 8) stage(buf, kt + 2);

        #pragma unroll
        for (int ks = 0; ks < 2; ++ks)
            #pragma unroll
            for (int m = 0; m < 4; ++m)
                #pragma unroll
                for (int n = 0; n < 4; ++n)
                    acc[m][n] = __builtin_amdgcn_mfma_f32_16x16x32_f16(
                        af[ks][m], bf[ks][n], acc[m][n], 0, 0, 0);
        buf ^= 1;
    }

    const int rowb = bm + wr*64 + (lane >> 4) * 4;
    #pragma unroll
    for (int n = 0; n < 4; ++n) {
        const int col = bn + wc*64 + n*16 + frow;
        if (col >= V_) continue;
        const float badd = bias[col];
        #pragma unroll
        for (int m = 0; m < 4; ++m) {
            const int r0 = rowb + m*16;
            #pragma unroll
            for (int r = 0; r < 4; ++r)
                __builtin_nontemporal_store(
                    acc[m][n][r] + badd,
                    &C[(size_t)(r0 + r) * (T_ * V_) + col]);
        }
    }
}

// ---------------------------------------------------------------------------
// Fused phase kernel: logical blocks [0,128) L0, [128,256) L1, [256,512) OUT;
// bx0 lets the host trim inactive head/tail ranges. 72 KB LDS -> 2 blocks/CU.
// XCD-aware bn ownership (round 8/9 verified).
// ---------------------------------------------------------------------------
__global__ __launch_bounds__(256)
void phase_kernel(const f16* __restrict__ h0in,
                  const f16* __restrict__ embt,
                  f16* __restrict__ h0out,
                  const f16* __restrict__ h1in,
                  f16* __restrict__ h1out,
                  const f16* __restrict__ W0p, const f16* __restrict__ W1p,
                  const f16* __restrict__ WoutP,
                  const f16* __restrict__ ctxg,
                  const float* __restrict__ bih1, const float* __restrict__ bhh1,
                  const float* __restrict__ b_out,
                  float* __restrict__ c0, float* __restrict__ c1,
                  float* __restrict__ out, int tout,
                  int bx0, int active0, int active1, int activeO)
{
    __shared__ char smem[73728];
    const int bx = blockIdx.x + bx0;

    if (bx < 128) {
        if (!active0) return;
        const int xcd = bx & 7, idx = bx >> 3;
        const int bn = (xcd*2 + (idx & 1)) * 128;
        const int bm = (idx >> 1) * 64;
        gemm_cell_body(h0in, embt, EW, W0p, 832,
                       ctxg, nullptr, nullptr, c0, h0out, smem, bm, bn);
    } else if (bx < 256) {
        if (!active1) return;
        const int lb = bx - 128;
        const int xcd = lb & 7, idx = lb >> 3;
        const int bn = (xcd*2 + (idx & 1)) * 128;
        const int bm = (idx >> 1) * 64;
        gemm_cell_body(h0in, h1in, 512, W1p, 1024,
                       nullptr, bih1, bhh1, c1, h1out, smem, bm, bn);
    } else {
        if (!activeO) return;
        const int o = bx - 256;                  // 0..255
        const int xcd = o & 7, j = o >> 3;       // j 0..31
        const int bnt = xcd*8 + (j >> 2);        // 0..63
        if (bnt >= 63) return;                   // 4 idle blocks
        const int bm = (j & 3) * 128;
        gemm_out_body(h1in, WoutP, out + (size_t)tout * V_, b_out,
                      bm, bnt * 128, smem, threadIdx.x);
    }
}

// ---------------------------------------------------------------------------
// ONE merged setup kernel (verified round 9).
// ---------------------------------------------------------------------------
#define NB_F16   1280
#define NB_WIC   2560
#define NB_W0    6656
#define NB_W1    8192
#define NB_WCTX  4096
#define NB_B0    8
#define NB_WOUT  4032
#define NB_EMB   10240
#define NB_TOTAL (NB_F16+NB_WIC+NB_W0+NB_W1+NB_WCTX+NB_B0+NB_WOUT+NB_EMB)

__global__ __launch_bounds__(256)
void pack_all(const float* __restrict__ fused,
              const float* __restrict__ Win, const float* __restrict__ Wcell,
              const float* __restrict__ Whh0, const float* __restrict__ Wih0,
              const float* __restrict__ Wih1, const float* __restrict__ Whh1,
              const float* __restrict__ bih0, const float* __restrict__ bhh0,
              const float* __restrict__ Wout,
              const float* __restrict__ emb, const int* __restrict__ target,
              f16* __restrict__ fused16, f16* __restrict__ WinCell,
              f16* __restrict__ W0, f16* __restrict__ W1,
              f16* __restrict__ Wc, float* __restrict__ b01p,
              f16* __restrict__ Wo, f16* __restrict__ embAll)
{
    int bx = blockIdx.x;
    const int tid = threadIdx.x;

    if (bx < NB_F16) {
        const int i = bx * 256 + tid;
        const float4 v = reinterpret_cast<const float4*>(fused)[i];
        f16x4 h = { (f16)v.x, (f16)v.y, (f16)v.z, (f16)v.w };
        *reinterpret_cast<f16x4*>(fused16 + (size_t)i * 4) = h;
        return;
    }
    bx -= NB_F16;
    if (bx < NB_WIC) {
        const int i = bx * 256 + tid;
        const int r = i / 640, c4 = (i % 640) * 4;
        const float* src = (r < 512) ? Win + (size_t)r * I_ + c4
                                     : Wcell + (size_t)(r - 512) * I_ + c4;
        const float4 v = *reinterpret_cast<const float4*>(src);
        f16x4 h = { (f16)v.x, (f16)v.y, (f16)v.z, (f16)v.w };
        *reinterpret_cast<f16x4*>(WinCell + (size_t)i * 4) = h;
        return;
    }
    bx -= NB_WIC;
    if (bx < NB_W0) {
        const int idx = bx * 256 + tid;
        const int rp = idx / 832, k = idx % 832;
        const int g = (rp >> 5) & 3, h = (rp >> 7) * 32 + (rp & 31);
        const int srow = g * 512 + h;
        float v;
        if (k < 512)      v = Whh0[(size_t)srow * 512 + k];
        else if (k < 812) v = Wih0[(size_t)srow * 812 + (k - 512)];
        else              v = 0.0f;
        W0[idx] = (f16)v;
        return;
    }
    bx -= NB_W0;
    if (bx < NB_W1) {
        const int idx = bx * 256 + tid;
        const int rp = idx >> 10, k = idx & 1023;
        const int g = (rp >> 5) & 3, h = (rp >> 7) * 32 + (rp & 31);
        const int srow = g * 512 + h;
        const float v = (k < 512) ? Wih1[(size_t)srow * 512 + k]
                                  : Whh1[(size_t)srow * 512 + (k - 512)];
        W1[idx] = (f16)v;
        return;
    }
    bx -= NB_W1;
    if (bx < NB_WCTX) {
        const int idx = bx * 256 + tid;
        const int rp = idx >> 9, k = idx & 511;
        const int g = (rp >> 5) & 3, h = (rp >> 7) * 32 + (rp & 31);
        Wc[idx] = (f16)Wih0[(size_t)(g * 512 + h) * 812 + 300 + k];
        return;
    }
    bx -= NB_WCTX;
    if (bx < NB_B0) {
        const int idx = bx * 256 + tid;
        const int g = (idx >> 5) & 3, h = (idx >> 7) * 32 + (idx & 31);
        b01p[idx] = bih0[g * 512 + h] + bhh0[g * 512 + h];
        return;
    }
    bx -= NB_B0;
    if (bx < NB_WOUT) {
        const int i = bx * 256 + tid;
        const int r = i >> 7, c4 = (i & 127) * 4;
        f16x4 h = { (f16)0.f, (f16)0.f, (f16)0.f, (f16)0.f };
        if (r < V_) {
            const float4 v = *reinterpret_cast<const float4*>(Wout + (size_t)r * H_ + c4);
            h = f16x4{ (f16)v.x, (f16)v.y, (f16)v.z, (f16)v.w };
        }
        *reinterpret_cast<f16x4*>(Wo + (size_t)i * 4) = h;
        return;
    }
    bx -= NB_WOUT;
    {
        const int idx = bx * 256 + tid;
        const int t = idx / (B_ * EW);
        const int rem = idx % (B_ * EW);
        const int b = rem / EW, e = rem % EW;
        const int wd = (t == 0) ? SOS_ : target[b * T_ + (t - 1)];
        const float v = (e < E_) ? emb[(size_t)wd * E_ + e] : 0.0f;
        embAll[idx] = (f16)v;
    }
}

// ---------------------------------------------------------------------------
extern "C" void kernel_launch(void* const* d_in, const int* in_sizes, int n_in,
                              void* d_out, int out_size, void* d_ws, size_t ws_size,
                              hipStream_t stream)
{
    const float* fused  = (const float*)d_in[0];
    const int*   target = (const int*)d_in[1];
    const float* emb    = (const float*)d_in[3];
    const float* W_in   = (const float*)d_in[4];
    const float* b_in   = (const float*)d_in[5];
    const float* W_cell = (const float*)d_in[6];
    const float* b_cell = (const float*)d_in[7];
    const float* W_ih0  = (const float*)d_in[8];
    const float* W_hh0  = (const float*)d_in[9];
    const float* b_ih0  = (const float*)d_in[10];
    const float* b_hh0  = (const float*)d_in[11];
    const float* W_ih1  = (const float*)d_in[12];
    const float* W_hh1  = (const float*)d_in[13];
    const float* b_ih1  = (const float*)d_in[14];
    const float* b_hh1  = (const float*)d_in[15];
    const float* W_out  = (const float*)d_in[16];
    const float* b_out  = (const float*)d_in[17];
    float* out = (float*)d_out;

    char* p = (char*)d_ws;
    auto carve = [&](size_t bytes) {
        char* r = p;
        p += (bytes + 255) & ~(size_t)255;
        return r;
    };
    f16* ctxg     = (f16*)carve((size_t)B_ * G4H * 2);
    float* b01p   = (float*)carve((size_t)G4H * 4);
    float* c0     = (float*)carve((size_t)B_ * H_ * 4);
    float* c1     = (float*)carve((size_t)B_ * H_ * 4);
    f16* fused16  = (f16*)carve((size_t)B_ * I_ * 2);
    f16* WinCell  = (f16*)carve((size_t)1024 * I_ * 2);
    f16* W0p      = (f16*)carve((size_t)G4H * 832 * 2);
    f16* W1p      = (f16*)carve((size_t)G4H * 1024 * 2);
    f16* Wctxp    = (f16*)carve((size_t)G4H * H_ * 2);
    f16* Wout16   = (f16*)carve((size_t)VPAD * H_ * 2);
    f16* ctx16    = (f16*)carve((size_t)B_ * H_ * 2);
    f16* h0a      = (f16*)carve((size_t)B_ * H_ * 2);
    f16* h0b      = (f16*)carve((size_t)B_ * H_ * 2);
    f16* h1a      = (f16*)carve((size_t)B_ * H_ * 2);
    f16* h1b      = (f16*)carve((size_t)B_ * H_ * 2);
    f16* embAll   = (f16*)carve((size_t)T_ * B_ * EW * 2);

    // ---- 1 merged pack launch ----
    pack_all<<<dim3(NB_TOTAL), 256, 0, stream>>>(
        fused, W_in, W_cell, W_hh0, W_ih0, W_ih1, W_hh1,
        b_ih0, b_hh0, W_out, emb, target,
        fused16, WinCell, W0p, W1p, Wctxp, b01p, Wout16, embAll);

    // ---- ctx/cell-init GEMM with fused init epilogue ----
    gemm_ctx_init<<<dim3(B_/128, 1024/128), 256, 0, stream>>>(
        fused16, WinCell, b_in, b_cell, ctx16, h0b, h1b, c0, c1);

    // ---- time-invariant ctx gate contribution (+ b0 biases), f16 out ----
    gemm_mfma_f16o<<<dim3(B_/128, G4H/128), 256, 0, stream>>>(
        ctx16, H_, Wctxp, H_, ctxg, G4H, H_, b01p);

    // ---- skewed recurrent + fused out-projection: phases 0..17 ----
    // Phase p: L0 -> h0(p); L1 -> h1(p-1); OUT -> logits(t = p-2).
    f16* h0buf[2] = { h0a, h0b };
    f16* h1buf[2] = { h1a, h1b };
    for (int phase = 0; phase <= T_ + 1; ++phase) {
        const int a0 = (phase < T_) ? 1 : 0;
        const int a1 = (phase >= 1 && phase <= T_) ? 1 : 0;
        const int aO = (phase >= 2) ? 1 : 0;
        const int te = (phase < T_) ? phase : (T_ - 1);
        const int tO = aO ? (phase - 2) : 0;
        int bx0 = 0, nb = 512;
        if (phase == 0)            { bx0 = 0;   nb = 128; }
        else if (phase == 1)       { bx0 = 0;   nb = 256; }
        else if (phase == T_)      { bx0 = 128; nb = 384; }   // L1 + OUT
        else if (phase == T_ + 1)  { bx0 = 256; nb = 256; }   // OUT only
        phase_kernel<<<dim3(nb), 256, 0, stream>>>(
            h0buf[(phase + 1) & 1],
            embAll + (size_t)te * B_ * EW,
            h0buf[phase & 1],
            h1buf[phase & 1],
            h1buf[(phase + 1) & 1],
            W0p, W1p, Wout16, ctxg, b_ih1, b_hh1, b_out,
            c0, c1, out, tO, bx0, a0, a1, aO);
    }
}

// Round 12
// 410.497 us; speedup vs baseline: 1.3735x; 1.0173x over previous
//
#include <hip/hip_runtime.h>
#include <cstdint>

#define B_   512
#define I_   2560
#define H_   512
#define E_   300
#define EW   320     // padded emb width
#define V_   8000
#define VPAD 8064    // 63 * 128
#define T_   16
#define G4H  2048
#define SOS_ 2

typedef _Float16 f16;
typedef _Float16 f16x8 __attribute__((ext_vector_type(8)));
typedef _Float16 f16x4 __attribute__((ext_vector_type(4)));
typedef float    f32x4 __attribute__((ext_vector_type(4)));

__device__ __forceinline__ float sigmoidf_(float x) {
    return 1.0f / (1.0f + __expf(-x));
}

__device__ __forceinline__ void gload16(const void* g, void* l) {
    __builtin_amdgcn_global_load_lds(
        (const __attribute__((address_space(1))) void*)g,
        (__attribute__((address_space(3))) void*)l,
        16, 0, 0);
}

// ---------------------------------------------------------------------------
// MFMA f16 GEMM (m97 structure) writing f16 C (+f32 bias) — ctxg producer.
// ---------------------------------------------------------------------------
__global__ __launch_bounds__(256)
void gemm_mfma_f16o(const f16* __restrict__ A, int lda,
                    const f16* __restrict__ Bw, int ldb,
                    f16* __restrict__ C, int ldc,
                    int K,
                    const float* __restrict__ bias1)
{
    __shared__ f16 As[128][32];
    __shared__ f16 Bs[128][32];

    const int tid  = threadIdx.x;
    const int w    = tid >> 6;
    const int lane = tid & 63;
    const int bm   = blockIdx.x * 128;
    const int bn   = blockIdx.y * 128;
    const int wr   = w >> 1;
    const int wc   = w & 1;

    const int srow = lane >> 2;
    const int skel = (lane & 3) * 8;

    const f16* Ag0 = A  + (size_t)(bm + w*32 +      srow) * lda + skel;
    const f16* Ag1 = A  + (size_t)(bm + w*32 + 16 + srow) * lda + skel;
    const f16* Bg0 = Bw + (size_t)(bn + w*32 +      srow) * ldb + skel;
    const f16* Bg1 = Bw + (size_t)(bn + w*32 + 16 + srow) * ldb + skel;
    f16* Al0 = &As[w*32     ][0];
    f16* Al1 = &As[w*32 + 16][0];
    f16* Bl0 = &Bs[w*32     ][0];
    f16* Bl1 = &Bs[w*32 + 16][0];

    const int frow = lane & 15;
    const int fk   = (lane >> 4) * 8;

    f32x4 acc[4][4] = {};

    for (int k0 = 0; k0 < K; k0 += 32) {
        gload16(Ag0 + k0, Al0);
        gload16(Ag1 + k0, Al1);
        gload16(Bg0 + k0, Bl0);
        gload16(Bg1 + k0, Bl1);
        __syncthreads();

        f16x8 af[4], bf[4];
        #pragma unroll
        for (int m = 0; m < 4; ++m)
            af[m] = *reinterpret_cast<const f16x8*>(&As[wr*64 + m*16 + frow][fk]);
        #pragma unroll
        for (int n = 0; n < 4; ++n)
            bf[n] = *reinterpret_cast<const f16x8*>(&Bs[wc*64 + n*16 + frow][fk]);

        #pragma unroll
        for (int m = 0; m < 4; ++m)
            #pragma unroll
            for (int n = 0; n < 4; ++n)
                acc[m][n] = __builtin_amdgcn_mfma_f32_16x16x32_f16(
                    af[m], bf[n], acc[m][n], 0, 0, 0);

        __syncthreads();
    }

    const int rowb = bm + wr*64 + (lane >> 4) * 4;
    #pragma unroll
    for (int n = 0; n < 4; ++n) {
        const int col = bn + wc*64 + n*16 + frow;
        const float badd = bias1 ? bias1[col] : 0.0f;
        #pragma unroll
        for (int m = 0; m < 4; ++m) {
            const int r0 = rowb + m*16;
            #pragma unroll
            for (int r = 0; r < 4; ++r)
                C[(size_t)(r0 + r) * ldc + col] = (f16)(acc[m][n][r] + badd);
        }
    }
}

// ---------------------------------------------------------------------------
// ctx/cell-init GEMM (verified round 9/11).
// ---------------------------------------------------------------------------
__global__ __launch_bounds__(256)
void gemm_ctx_init(const f16* __restrict__ A,
                   const f16* __restrict__ Bw,
                   const float* __restrict__ b_in,
                   const float* __restrict__ b_cell,
                   f16* __restrict__ ctx16,
                   f16* __restrict__ h0, f16* __restrict__ h1,
                   float* __restrict__ c0, float* __restrict__ c1)
{
    __shared__ f16 As[128][32];
    __shared__ f16 Bs[128][32];

    const int tid  = threadIdx.x;
    const int w    = tid >> 6;
    const int lane = tid & 63;
    const int bm   = blockIdx.x * 128;
    const int bn   = blockIdx.y * 128;
    const int wr   = w >> 1;
    const int wc   = w & 1;

    const int srow = lane >> 2;
    const int skel = (lane & 3) * 8;

    const f16* Ag0 = A  + (size_t)(bm + w*32 +      srow) * I_ + skel;
    const f16* Ag1 = A  + (size_t)(bm + w*32 + 16 + srow) * I_ + skel;
    const f16* Bg0 = Bw + (size_t)(bn + w*32 +      srow) * I_ + skel;
    const f16* Bg1 = Bw + (size_t)(bn + w*32 + 16 + srow) * I_ + skel;
    f16* Al0 = &As[w*32     ][0];
    f16* Al1 = &As[w*32 + 16][0];
    f16* Bl0 = &Bs[w*32     ][0];
    f16* Bl1 = &Bs[w*32 + 16][0];

    const int frow = lane & 15;
    const int fk   = (lane >> 4) * 8;

    f32x4 acc[4][4] = {};

    for (int k0 = 0; k0 < I_; k0 += 32) {
        gload16(Ag0 + k0, Al0);
        gload16(Ag1 + k0, Al1);
        gload16(Bg0 + k0, Bl0);
        gload16(Bg1 + k0, Bl1);
        __syncthreads();

        f16x8 af[4], bf[4];
        #pragma unroll
        for (int m = 0; m < 4; ++m)
            af[m] = *reinterpret_cast<const f16x8*>(&As[wr*64 + m*16 + frow][fk]);
        #pragma unroll
        for (int n = 0; n < 4; ++n)
            bf[n] = *reinterpret_cast<const f16x8*>(&Bs[wc*64 + n*16 + frow][fk]);

        #pragma unroll
        for (int m = 0; m < 4; ++m)
            #pragma unroll
            for (int n = 0; n < 4; ++n)
                acc[m][n] = __builtin_amdgcn_mfma_f32_16x16x32_f16(
                    af[m], bf[n], acc[m][n], 0, 0, 0);

        __syncthreads();
    }

    const int rowb = bm + wr*64 + (lane >> 4) * 4;
    #pragma unroll
    for (int n = 0; n < 4; ++n) {
        const int col = bn + wc*64 + n*16 + frow;
        #pragma unroll
        for (int m = 0; m < 4; ++m) {
            const int r0 = rowb + m*16;
            #pragma unroll
            for (int r = 0; r < 4; ++r) {
                const int row = r0 + r;
                if (col < 512) {
                    const f16 ch = (f16)(acc[m][n][r] + b_in[col]);
                    ctx16[(size_t)row * 512 + col] = ch;
                    h0[(size_t)row * 512 + col] = ch;
                    h1[(size_t)row * 512 + col] = ch;
                } else {
                    const float cc = acc[m][n][r] + b_cell[col - 512];
                    c0[(size_t)row * 512 + col - 512] = cc;
                    c1[(size_t)row * 512 + col - 512] = cc;
                }
            }
        }
    }
}

// ---------------------------------------------------------------------------
// Recurrent GEMM + fused LSTM cell body: SINGLE-BARRIER pipeline.
// NB=3 buffers, issue-distance D=2 => NB >= D+1, so the post-read barrier is
// provably unnecessary: a wave stages tile kt+2 into buf (kt+2)%3 = the buffer
// last read at iter kt-1, and every wave's iter-(kt-1) ds_reads landed before
// it reached barrier[kt] (compiler lgkm waits precede the consuming MFMAs).
// LDS: Abuf 3x8K @0, Wbuf 3x16K @24K (72 KB). Steady s_waitcnt vmcnt(6).
// ---------------------------------------------------------------------------
__device__ __forceinline__ void gemm_cell_body(
    const f16* __restrict__ Ap1, const f16* __restrict__ Ap2, int lda2,
    const f16* __restrict__ Wp, int K,
    const f16* __restrict__ Cadd,
    const float* __restrict__ bih, const float* __restrict__ bhh,
    float* __restrict__ cst,
    f16* __restrict__ hout1,
    char* smem, int bm, int bn)
{
    const int tid  = threadIdx.x;
    const int w    = tid >> 6;
    const int lane = tid & 63;
    const int wr   = w >> 1, wc = w & 1;
    const int frow = lane & 15, hi = lane >> 4;
    const int sw   = (frow & 7) << 4;
    const int srow8 = lane >> 3;
    const int ksb  = ((((lane & 7) * 16) ^ (srow8 << 4)) >> 1);

    const int NT = K >> 6;
    f32x4 acc[2][4] = {};

    char* Abuf = smem;            // 3 x 8192
    char* Wbuf = smem + 24576;    // 3 x 16384

    auto stage = [&](int bsel, int kt) {
        const int k0 = kt << 6;
        #pragma unroll
        for (int j = 0; j < 2; ++j) {
            const int row = w*16 + j*8 + srow8;
            const f16* src;
            if (k0 < 512) src = Ap1 + (size_t)(bm + row) * 512  + k0 + ksb;
            else          src = Ap2 + (size_t)(bm + row) * lda2 + (k0 - 512) + ksb;
            gload16(src, Abuf + bsel*8192 + (w*2 + j)*1024 + lane*16);
        }
        #pragma unroll
        for (int j = 0; j < 4; ++j) {
            const int row = w*32 + j*8 + srow8;
            gload16(Wp + (size_t)(bn + row) * K + k0 + ksb,
                    Wbuf + bsel*16384 + (w*4 + j)*1024 + lane*16);
        }
    };

    stage(0, 0);
    stage(1, 1);

    int rb = 0;                                  // read buffer = kt % 3
    for (int kt = 0; kt < NT; ++kt) {
        if (kt < NT - 1) asm volatile("s_waitcnt vmcnt(6)" ::: "memory");
        else             asm volatile("s_waitcnt vmcnt(0)" ::: "memory");
        __builtin_amdgcn_sched_barrier(0);
        __builtin_amdgcn_s_barrier();            // tile kt visible to all
        __builtin_amdgcn_sched_barrier(0);       // pin stage below the barrier

        const char* A_ = Abuf + rb*8192;
        const char* W_ = Wbuf + rb*16384;
        f16x8 af[2][2], bf[2][4];
        #pragma unroll
        for (int ks = 0; ks < 2; ++ks) {
            const int cb = (ks*64 + hi*16) ^ sw;
            #pragma unroll
            for (int m = 0; m < 2; ++m)
                af[ks][m] = *reinterpret_cast<const f16x8*>(A_ + (wr*32 + m*16 + frow)*128 + cb);
            #pragma unroll
            for (int n = 0; n < 4; ++n)
                bf[ks][n] = *reinterpret_cast<const f16x8*>(W_ + (wc*64 + n*16 + frow)*128 + cb);
        }

        if (kt + 2 < NT) {
            int sb = rb - 1; if (sb < 0) sb = 2;   // (rb+2)%3
            stage(sb, kt + 2);
        }

        #pragma unroll
        for (int ks = 0; ks < 2; ++ks)
            #pragma unroll
            for (int m = 0; m < 2; ++m)
                #pragma unroll
                for (int n = 0; n < 4; ++n)
                    acc[m][n] = __builtin_amdgcn_mfma_f32_16x16x32_f16(
                        af[ks][m], bf[ks][n], acc[m][n], 0, 0, 0);
        rb = (rb == 2) ? 0 : rb + 1;
    }
    __syncthreads();               // all waves done with LDS bufs -> alias gs

    // gates -> LDS (+ Cadd f16), f32 [64][132]
    float* gs = (float*)smem;
    #pragma unroll
    for (int m = 0; m < 2; ++m) {
        const int row = wr*32 + m*16 + hi*4;
        #pragma unroll
        for (int n = 0; n < 4; ++n) {
            const int col = wc*64 + n*16 + frow;
            #pragma unroll
            for (int r = 0; r < 4; ++r) {
                float v = acc[m][n][r];
                if (Cadd) v += (float)Cadd[(size_t)(bm + row + r) * G4H + bn + col];
                gs[(row + r)*132 + col] = v;
            }
        }
    }
    __syncthreads();

    const int hp = tid & 31;
    const int hg = (bn >> 2) + hp;
    float bi0 = 0.f, bi1 = 0.f, bi2 = 0.f, bi3 = 0.f;
    if (bih) {
        bi0 = bih[hg]        + bhh[hg];
        bi1 = bih[512 + hg]  + bhh[512 + hg];
        bi2 = bih[1024 + hg] + bhh[1024 + hg];
        bi3 = bih[1536 + hg] + bhh[1536 + hg];
    }
    #pragma unroll
    for (int i = 0; i < 8; ++i) {
        const int r = (tid >> 5) * 8 + i;
        const int b = bm + r;
        const float gi = gs[r*132 +      hp] + bi0;
        const float gf = gs[r*132 + 32 + hp] + bi1;
        const float gc = gs[r*132 + 64 + hp] + bi2;
        const float go = gs[r*132 + 96 + hp] + bi3;
        const float c  = cst[(size_t)b * 512 + hg];
        const float cn = sigmoidf_(gf) * c + sigmoidf_(gi) * tanhf(gc);
        const float hn = sigmoidf_(go) * tanhf(cn);
        cst[(size_t)b * 512 + hg] = cn;
        hout1[(size_t)b * 512 + hg] = (f16)hn;
    }
}

// ---------------------------------------------------------------------------
// Output-projection tile body (round-9/11 verified): BK=64, XOR-swizzled,
// depth-2 counted vmcnt, nontemporal C stores. LDS: A 2x16K @0, W 2x16K @32K.
// ---------------------------------------------------------------------------
__device__ __forceinline__ void gemm_out_body(
    const f16* __restrict__ A, const f16* __restrict__ Bw,
    float* __restrict__ C,     // = out + t*V_
    const float* __restrict__ bias,
    int bm, int bn, char* smem, int tid)
{
    const int w    = tid >> 6;
    const int lane = tid & 63;
    const int wr   = w >> 1, wc = w & 1;
    const int frow = lane & 15, hi = lane >> 4;
    const int sw   = (frow & 7) << 4;
    const int srow8 = lane >> 3;
    const int ksb  = ((((lane & 7) * 16) ^ (srow8 << 4)) >> 1);

    char* Abuf = smem;            // 2 x 16384
    char* Wbuf = smem + 32768;    // 2 x 16384
    f32x4 acc[4][4] = {};

    auto stage = [&](int bsel, int kt) {
        const int k0 = kt << 6;
        #pragma unroll
        for (int j = 0; j < 4; ++j) {
            const int row = w*32 + j*8 + srow8;
            gload16(A  + (size_t)(bm + row) * 512 + k0 + ksb,
                    Abuf + bsel*16384 + (w*4 + j)*1024 + lane*16);
            gload16(Bw + (size_t)(bn + row) * 512 + k0 + ksb,
                    Wbuf + bsel*16384 + (w*4 + j)*1024 + lane*16);
        }
    };

    stage(0, 0);
    stage(1, 1);

    int buf = 0;
    for (int kt = 0; kt < 8; ++kt) {
        if (kt < 7) asm volatile("s_waitcnt vmcnt(8)" ::: "memory");
        else        asm volatile("s_waitcnt vmcnt(0)" ::: "memory");
        __builtin_amdgcn_sched_barrier(0);
        __builtin_amdgcn_s_barrier();
        __builtin_amdgcn_sched_barrier(0);

        const char* A_ = Abuf + buf*16384;
        const char* W_ = Wbuf + buf*16384;
        f16x8 af[2][4], bf[2][4];
        #pragma unroll
        for (int ks = 0; ks < 2; ++ks) {
            const int cb = (ks*64 + hi*16) ^ sw;
            #pragma unroll
            for (int m = 0; m < 4; ++m)
                af[ks][m] = *reinterpret_cast<const f16x8*>(A_ + (wr*64 + m*16 + frow)*128 + cb);
            #pragma unroll
            for (int n = 0; n < 4; ++n)
                bf[ks][n] = *reinterpret_cast<const f16x8*>(W_ + (wc*64 + n*16 + frow)*128 + cb);
        }
        __builtin_amdgcn_sched_barrier(0);
        asm volatile("s_waitcnt lgkmcnt(0)" ::: "memory");
        __builtin_amdgcn_sched_barrier(0);
        __builtin_amdgcn_s_barrier();
        __builtin_amdgcn_sched_barrier(0);

        if (kt + 2 < 8) stage(buf, kt + 2);

        #pragma unroll
        for (int ks = 0; ks < 2; ++ks)
            #pragma unroll
            for (int m = 0; m < 4; ++m)
                #pragma unroll
                for (int n = 0; n < 4; ++n)
                    acc[m][n] = __builtin_amdgcn_mfma_f32_16x16x32_f16(
                        af[ks][m], bf[ks][n], acc[m][n], 0, 0, 0);
        buf ^= 1;
    }

    const int rowb = bm + wr*64 + (lane >> 4) * 4;
    #pragma unroll
    for (int n = 0; n < 4; ++n) {
        const int col = bn + wc*64 + n*16 + frow;
        if (col >= V_) continue;
        const float badd = bias[col];
        #pragma unroll
        for (int m = 0; m < 4; ++m) {
            const int r0 = rowb + m*16;
            #pragma unroll
            for (int r = 0; r < 4; ++r)
                __builtin_nontemporal_store(
                    acc[m][n][r] + badd,
                    &C[(size_t)(r0 + r) * (T_ * V_) + col]);
        }
    }
}

// ---------------------------------------------------------------------------
// Fused phase kernel: logical blocks [0,128) L0, [128,256) L1, [256,512) OUT;
// bx0 trims inactive head/tail ranges. 72 KB LDS -> 2 blocks/CU.
// XCD-aware bn ownership (round 8/9 verified).
// ---------------------------------------------------------------------------
__global__ __launch_bounds__(256)
void phase_kernel(const f16* __restrict__ h0in,
                  const f16* __restrict__ embt,
                  f16* __restrict__ h0out,
                  const f16* __restrict__ h1in,
                  f16* __restrict__ h1out,
                  const f16* __restrict__ W0p, const f16* __restrict__ W1p,
                  const f16* __restrict__ WoutP,
                  const f16* __restrict__ ctxg,
                  const float* __restrict__ bih1, const float* __restrict__ bhh1,
                  const float* __restrict__ b_out,
                  float* __restrict__ c0, float* __restrict__ c1,
                  float* __restrict__ out, int tout,
                  int bx0, int active0, int active1, int activeO)
{
    __shared__ char smem[73728];
    const int bx = blockIdx.x + bx0;

    if (bx < 128) {
        if (!active0) return;
        const int xcd = bx & 7, idx = bx >> 3;
        const int bn = (xcd*2 + (idx & 1)) * 128;
        const int bm = (idx >> 1) * 64;
        gemm_cell_body(h0in, embt, EW, W0p, 832,
                       ctxg, nullptr, nullptr, c0, h0out, smem, bm, bn);
    } else if (bx < 256) {
        if (!active1) return;
        const int lb = bx - 128;
        const int xcd = lb & 7, idx = lb >> 3;
        const int bn = (xcd*2 + (idx & 1)) * 128;
        const int bm = (idx >> 1) * 64;
        gemm_cell_body(h0in, h1in, 512, W1p, 1024,
                       nullptr, bih1, bhh1, c1, h1out, smem, bm, bn);
    } else {
        if (!activeO) return;
        const int o = bx - 256;                  // 0..255
        const int xcd = o & 7, j = o >> 3;       // j 0..31
        const int bnt = xcd*8 + (j >> 2);        // 0..63
        if (bnt >= 63) return;                   // 4 idle blocks
        const int bm = (j & 3) * 128;
        gemm_out_body(h1in, WoutP, out + (size_t)tout * V_, b_out,
                      bm, bnt * 128, smem, threadIdx.x);
    }
}

// ---------------------------------------------------------------------------
// ONE merged setup kernel, float4-vectorized segments (4 elems/thread).
// ---------------------------------------------------------------------------
#define NB_F16   1280                 // fused16: 512*2560/4/256
#define NB_WIC   2560                 // WinCell: 1024*2560/4/256
#define NB_W0    1664                 // W0p: 2048*208/256
#define NB_W1    2048                 // W1p: 2048*256/256
#define NB_WCTX  1024                 // Wctxp: 2048*128/256
#define NB_B0    8
#define NB_WOUT  4032                 // Wout16: 8064*128/256
#define NB_EMB   2560                 // embAll: 16*512*80/256
#define NB_TOTAL (NB_F16+NB_WIC+NB_W0+NB_W1+NB_WCTX+NB_B0+NB_WOUT+NB_EMB)

__global__ __launch_bounds__(256)
void pack_all(const float* __restrict__ fused,
              const float* __restrict__ Win, const float* __restrict__ Wcell,
              const float* __restrict__ Whh0, const float* __restrict__ Wih0,
              const float* __restrict__ Wih1, const float* __restrict__ Whh1,
              const float* __restrict__ bih0, const float* __restrict__ bhh0,
              const float* __restrict__ Wout,
              const float* __restrict__ emb, const int* __restrict__ target,
              f16* __restrict__ fused16, f16* __restrict__ WinCell,
              f16* __restrict__ W0, f16* __restrict__ W1,
              f16* __restrict__ Wc, float* __restrict__ b01p,
              f16* __restrict__ Wo, f16* __restrict__ embAll)
{
    int bx = blockIdx.x;
    const int tid = threadIdx.x;

    auto cvt4 = [](float4 v) {
        return f16x4{ (f16)v.x, (f16)v.y, (f16)v.z, (f16)v.w };
    };

    if (bx < NB_F16) {
        const int i = bx * 256 + tid;
        *reinterpret_cast<f16x4*>(fused16 + (size_t)i * 4) =
            cvt4(reinterpret_cast<const float4*>(fused)[i]);
        return;
    }
    bx -= NB_F16;
    if (bx < NB_WIC) {
        const int i = bx * 256 + tid;
        const int r = i / 640, c4 = (i % 640) * 4;
        const float* src = (r < 512) ? Win + (size_t)r * I_ + c4
                                     : Wcell + (size_t)(r - 512) * I_ + c4;
        *reinterpret_cast<f16x4*>(WinCell + (size_t)i * 4) =
            cvt4(*reinterpret_cast<const float4*>(src));
        return;
    }
    bx -= NB_WIC;
    if (bx < NB_W0) {
        const int idx = bx * 256 + tid;       // 2048*208
        const int rp = idx / 208, k = (idx % 208) * 4;
        const int g = (rp >> 5) & 3, h = (rp >> 7) * 32 + (rp & 31);
        const int srow = g * 512 + h;
        f16x4 o = { (f16)0.f, (f16)0.f, (f16)0.f, (f16)0.f };
        if (k < 512)
            o = cvt4(*reinterpret_cast<const float4*>(Whh0 + (size_t)srow * 512 + k));
        else if (k < 812)
            o = cvt4(*reinterpret_cast<const float4*>(Wih0 + (size_t)srow * 812 + (k - 512)));
        *reinterpret_cast<f16x4*>(W0 + (size_t)rp * 832 + k) = o;
        return;
    }
    bx -= NB_W0;
    if (bx < NB_W1) {
        const int idx = bx * 256 + tid;       // 2048*256
        const int rp = idx >> 8, k = (idx & 255) * 4;
        const int g = (rp >> 5) & 3, h = (rp >> 7) * 32 + (rp & 31);
        const int srow = g * 512 + h;
        const float* src = (k < 512) ? Wih1 + (size_t)srow * 512 + k
                                     : Whh1 + (size_t)srow * 512 + (k - 512);
        *reinterpret_cast<f16x4*>(W1 + (size_t)rp * 1024 + k) =
            cvt4(*reinterpret_cast<const float4*>(src));
        return;
    }
    bx -= NB_W1;
    if (bx < NB_WCTX) {
        const int idx = bx * 256 + tid;       // 2048*128
        const int rp = idx >> 7, k = (idx & 127) * 4;
        const int g = (rp >> 5) & 3, h = (rp >> 7) * 32 + (rp & 31);
        *reinterpret_cast<f16x4*>(Wc + (size_t)rp * 512 + k) =
            cvt4(*reinterpret_cast<const float4*>(
                Wih0 + (size_t)(g * 512 + h) * 812 + 300 + k));
        return;
    }
    bx -= NB_WCTX;
    if (bx < NB_B0) {
        const int idx = bx * 256 + tid;
        const int g = (idx >> 5) & 3, h = (idx >> 7) * 32 + (idx & 31);
        b01p[idx] = bih0[g * 512 + h] + bhh0[g * 512 + h];
        return;
    }
    bx -= NB_B0;
    if (bx < NB_WOUT) {
        const int i = bx * 256 + tid;
        const int r = i >> 7, c4 = (i & 127) * 4;
        f16x4 o = { (f16)0.f, (f16)0.f, (f16)0.f, (f16)0.f };
        if (r < V_)
            o = cvt4(*reinterpret_cast<const float4*>(Wout + (size_t)r * H_ + c4));
        *reinterpret_cast<f16x4*>(Wo + (size_t)i * 4) = o;
        return;
    }
    bx -= NB_WOUT;
    {
        const int idx = bx * 256 + tid;       // 16*512*80
        const int t = idx / (B_ * 80);
        const int rem = idx % (B_ * 80);
        const int b = rem / 80, e = (rem % 80) * 4;
        const int wd = (t == 0) ? SOS_ : target[b * T_ + (t - 1)];
        f16x4 o = { (f16)0.f, (f16)0.f, (f16)0.f, (f16)0.f };
        if (e < E_)
            o = cvt4(*reinterpret_cast<const float4*>(emb + (size_t)wd * E_ + e));
        *reinterpret_cast<f16x4*>(embAll + ((size_t)t * B_ + b) * EW + e) = o;
    }
}

// ---------------------------------------------------------------------------
extern "C" void kernel_launch(void* const* d_in, const int* in_sizes, int n_in,
                              void* d_out, int out_size, void* d_ws, size_t ws_size,
                              hipStream_t stream)
{
    const float* fused  = (const float*)d_in[0];
    const int*   target = (const int*)d_in[1];
    const float* emb    = (const float*)d_in[3];
    const float* W_in   = (const float*)d_in[4];
    const float* b_in   = (const float*)d_in[5];
    const float* W_cell = (const float*)d_in[6];
    const float* b_cell = (const float*)d_in[7];
    const float* W_ih0  = (const float*)d_in[8];
    const float* W_hh0  = (const float*)d_in[9];
    const float* b_ih0  = (const float*)d_in[10];
    const float* b_hh0  = (const float*)d_in[11];
    const float* W_ih1  = (const float*)d_in[12];
    const float* W_hh1  = (const float*)d_in[13];
    const float* b_ih1  = (const float*)d_in[14];
    const float* b_hh1  = (const float*)d_in[15];
    const float* W_out  = (const float*)d_in[16];
    const float* b_out  = (const float*)d_in[17];
    float* out = (float*)d_out;

    char* p = (char*)d_ws;
    auto carve = [&](size_t bytes) {
        char* r = p;
        p += (bytes + 255) & ~(size_t)255;
        return r;
    };
    f16* ctxg     = (f16*)carve((size_t)B_ * G4H * 2);
    float* b01p   = (float*)carve((size_t)G4H * 4);
    float* c0     = (float*)carve((size_t)B_ * H_ * 4);
    float* c1     = (float*)carve((size_t)B_ * H_ * 4);
    f16* fused16  = (f16*)carve((size_t)B_ * I_ * 2);
    f16* WinCell  = (f16*)carve((size_t)1024 * I_ * 2);
    f16* W0p      = (f16*)carve((size_t)G4H * 832 * 2);
    f16* W1p      = (f16*)carve((size_t)G4H * 1024 * 2);
    f16* Wctxp    = (f16*)carve((size_t)G4H * H_ * 2);
    f16* Wout16   = (f16*)carve((size_t)VPAD * H_ * 2);
    f16* ctx16    = (f16*)carve((size_t)B_ * H_ * 2);
    f16* h0a      = (f16*)carve((size_t)B_ * H_ * 2);
    f16* h0b      = (f16*)carve((size_t)B_ * H_ * 2);
    f16* h1a      = (f16*)carve((size_t)B_ * H_ * 2);
    f16* h1b      = (f16*)carve((size_t)B_ * H_ * 2);
    f16* embAll   = (f16*)carve((size_t)T_ * B_ * EW * 2);

    // ---- 1 merged pack launch (vectorized) ----
    pack_all<<<dim3(NB_TOTAL), 256, 0, stream>>>(
        fused, W_in, W_cell, W_hh0, W_ih0, W_ih1, W_hh1,
        b_ih0, b_hh0, W_out, emb, target,
        fused16, WinCell, W0p, W1p, Wctxp, b01p, Wout16, embAll);

    // ---- ctx/cell-init GEMM with fused init epilogue ----
    gemm_ctx_init<<<dim3(B_/128, 1024/128), 256, 0, stream>>>(
        fused16, WinCell, b_in, b_cell, ctx16, h0b, h1b, c0, c1);

    // ---- time-invariant ctx gate contribution (+ b0 biases), f16 out ----
    gemm_mfma_f16o<<<dim3(B_/128, G4H/128), 256, 0, stream>>>(
        ctx16, H_, Wctxp, H_, ctxg, G4H, H_, b01p);

    // ---- skewed recurrent + fused out-projection: phases 0..17 ----
    // Phase p: L0 -> h0(p); L1 -> h1(p-1); OUT -> logits(t = p-2).
    f16* h0buf[2] = { h0a, h0b };
    f16* h1buf[2] = { h1a, h1b };
    for (int phase = 0; phase <= T_ + 1; ++phase) {
        const int a0 = (phase < T_) ? 1 : 0;
        const int a1 = (phase >= 1 && phase <= T_) ? 1 : 0;
        const int aO = (phase >= 2) ? 1 : 0;
        const int te = (phase < T_) ? phase : (T_ - 1);
        const int tO = aO ? (phase - 2) : 0;
        int bx0 = 0, nb = 512;
        if (phase == 0)            { bx0 = 0;   nb = 128; }
        else if (phase == 1)       { bx0 = 0;   nb = 256; }
        else if (phase == T_)      { bx0 = 128; nb = 384; }   // L1 + OUT
        else if (phase == T_ + 1)  { bx0 = 256; nb = 256; }   // OUT only
        phase_kernel<<<dim3(nb), 256, 0, stream>>>(
            h0buf[(phase + 1) & 1],
            embAll + (size_t)te * B_ * EW,
            h0buf[phase & 1],
            h1buf[phase & 1],
            h1buf[(phase + 1) & 1],
            W0p, W1p, Wout16, ctxg, b_ih1, b_hh1, b_out,
            c0, c1, out, tO, bx0, a0, a1, aO);
    }
}